// Round 6
// baseline (36.555 us; speedup 1.0000x reference)
//
#include <hip/hip_runtime.h>
#include <math.h>

// SoftHd via bf16 MFMA, K-quartered double-buffered pipeline.
// v1: (64,128,128) f32, sz1: (64,), v2: (64,128,128) f32, sz2: (64,), out (64,64) f32.
// out[b1,b2] = sum_{j<sz2} min_{i<sz1} dist[i,j] + sum_{i<sz1} min_{j<sz2} dist[i,j]
// dist via gemm identity on bf16-rounded inputs (MFMA 16x16x32_bf16).
// sqrt is monotone -> mins on squared distances, sqrt after reduction.
// Pre-kernel emits a quarter-blocked bf16 layout:
//   panel byte offset(r, c16) = (c16>>2)*8192 + (r>>3)*512 + (c16&3)*128 + (r&7)*16
// so each K-quarter is a contiguous 8 KB block: staging is a LINEAR copy
// (coalesced source, linear global_load_lds dest) and fragment ds_read_b128s
// spread 16 lanes over 8 16B slots (2-way aliasing = free, no swizzle).

typedef __attribute__((ext_vector_type(8))) short short8;
typedef __attribute__((ext_vector_type(4))) float f32x4;
typedef unsigned int u32;
typedef unsigned short ushort_t;

static __device__ __forceinline__ ushort_t f32_to_bf16_rne(float f) {
    u32 b = __float_as_uint(f);
    b += 0x7FFFu + ((b >> 16) & 1u);
    return (ushort_t)(b >> 16);
}

// ---------------------------------------------------------------------------
// Pre-kernel: f32 -> bf16 into the quarter-blocked layout + per-row squared
// norms (fp32 of the ROUNDED values).
// ---------------------------------------------------------------------------
__global__ __launch_bounds__(256) void softhd_pre(
    const float* __restrict__ v1, const float* __restrict__ v2,
    ushort_t* __restrict__ v1b, ushort_t* __restrict__ v2b,
    float* __restrict__ x2g, float* __restrict__ y2g)
{
    int flat = blockIdx.x * 256 + threadIdx.x;
    int c = flat & 15;                 // 16B chunk within row (k-chunk)
    int r = (flat >> 4) & 127;         // row
    int b = (flat >> 11) & 63;         // batch
    int t = flat >> 17;                // tensor select

    const float* src = (t ? v2 : v1) + ((size_t)((b << 7) + r) << 7) + c * 8;
    char* dstp = (char*)((t ? v2b : v1b) + ((size_t)b << 14));

    float4 q0 = *(const float4*)(src);
    float4 q1 = *(const float4*)(src + 4);

    ushort_t h[8];
    h[0] = f32_to_bf16_rne(q0.x); h[1] = f32_to_bf16_rne(q0.y);
    h[2] = f32_to_bf16_rne(q0.z); h[3] = f32_to_bf16_rne(q0.w);
    h[4] = f32_to_bf16_rne(q1.x); h[5] = f32_to_bf16_rne(q1.y);
    h[6] = f32_to_bf16_rne(q1.z); h[7] = f32_to_bf16_rne(q1.w);

    float p = 0.f;
#pragma unroll
    for (int k = 0; k < 8; ++k) {
        float fv = __uint_as_float((u32)h[k] << 16);
        p += fv * fv;
    }

    uint4 w;
    w.x = (u32)h[0] | ((u32)h[1] << 16);
    w.y = (u32)h[2] | ((u32)h[3] << 16);
    w.z = (u32)h[4] | ((u32)h[5] << 16);
    w.w = (u32)h[6] | ((u32)h[7] << 16);

    int off = ((c >> 2) << 13) + ((r >> 3) << 9) + ((c & 3) << 7) + ((r & 7) << 4);
    *(uint4*)(dstp + off) = w;

    p += __shfl_xor(p, 1);
    p += __shfl_xor(p, 2);
    p += __shfl_xor(p, 4);
    p += __shfl_xor(p, 8);
    if (c == 0) (t ? y2g : x2g)[(b << 7) + r] = p;
}

// ---------------------------------------------------------------------------
// Main kernel: one block per (b1,b2). 4 waves, 2x2 quadrant split (64x64 out
// per wave). K in 4 quarters of 32, double-buffered (T3 2-phase pipeline).
// ---------------------------------------------------------------------------
__global__ __launch_bounds__(256, 4) void softhd_mfma(
    const ushort_t* __restrict__ v1b, const ushort_t* __restrict__ v2b,
    const float* __restrict__ x2g, const float* __restrict__ y2g,
    const int* __restrict__ sz1, const int* __restrict__ sz2,
    float* __restrict__ out)
{
    __shared__ __align__(16) ushort_t sb[2][2][4096];  // [buf][panel][8 KB]
    __shared__ float sx2[128], sy2[128];
    __shared__ u32 sbm1[128], sbm2[128];
    __shared__ float swsum[4];

    const int tid = threadIdx.x;
    const int lane = tid & 63;
    const int wid = tid >> 6;
    // XCD-bijective swizzle (4096 % 8 == 0).
    const int bid = ((blockIdx.x & 7) << 9) | (blockIdx.x >> 3);
    const int b1 = bid >> 6, b2 = bid & 63;

    const char* gp0 = (const char*)(v1b + ((size_t)b1 << 14));
    const char* gp1 = (const char*)(v2b + ((size_t)b2 << 14));

#define STAGE(d, q)                                                          \
    {                                                                        \
        _Pragma("unroll")                                                    \
        for (int e = 0; e < 2; ++e) {                                        \
            int m16 = ((e << 8) + tid) << 4;                                 \
            __builtin_amdgcn_global_load_lds(                                \
                (const __attribute__((address_space(1))) u32*)(gp0 + ((q) << 13) + m16), \
                (__attribute__((address_space(3))) u32*)((char*)&sb[d][0][0] + m16),     \
                16, 0, 0);                                                   \
            __builtin_amdgcn_global_load_lds(                                \
                (const __attribute__((address_space(1))) u32*)(gp1 + ((q) << 13) + m16), \
                (__attribute__((address_space(3))) u32*)((char*)&sb[d][1][0] + m16),     \
                16, 0, 0);                                                   \
        }                                                                    \
    }

    STAGE(0, 0);

    const int n1 = min(max(sz1[b1], 0), 128);
    const int n2 = min(max(sz2[b2], 0), 128);

    if (tid < 128) {
        sx2[tid] = x2g[(b1 << 7) + tid];
        sbm1[tid] = 0x7F800000u;            // +inf bits
    } else {
        sy2[tid - 128] = y2g[(b2 << 7) + (tid - 128)];
        sbm2[tid - 128] = 0x7F800000u;
    }
    __syncthreads();                         // buf0 resident

    const int qr = wid >> 1, qc = wid & 1;
    const int ibase = qr << 6, jbase = qc << 6;
    const int rf = lane & 15, kg = lane >> 4;

    // frag elem offsets within an 8 KB quarter buffer:
    // off(row) = (row>>3)*256 + kg*64 + (row&7)*8   (elements)
    int aoff[4], boff[4];
#pragma unroll
    for (int f = 0; f < 4; ++f) {
        int ra = ibase + (f << 4) + rf;
        int rb = jbase + (f << 4) + rf;
        aoff[f] = ((ra >> 3) << 8) + (kg << 6) + ((ra & 7) << 3);
        boff[f] = ((rb >> 3) << 8) + (kg << 6) + ((rb & 7) << 3);
    }

    f32x4 acc[4][4];
#pragma unroll
    for (int fi = 0; fi < 4; ++fi)
#pragma unroll
        for (int fj = 0; fj < 4; ++fj)
            acc[fi][fj] = (f32x4){0.f, 0.f, 0.f, 0.f};

#pragma unroll
    for (int q = 0; q < 4; ++q) {
        const int d = q & 1;
        if (q < 3) STAGE(d ^ 1, q + 1);      // issue next quarter's loads
        short8 a[4], b[4];
#pragma unroll
        for (int f = 0; f < 4; ++f) {
            a[f] = *(const short8*)(&sb[d][0][0] + aoff[f]);
            b[f] = *(const short8*)(&sb[d][1][0] + boff[f]);
        }
#pragma unroll
        for (int fi = 0; fi < 4; ++fi)
#pragma unroll
            for (int fj = 0; fj < 4; ++fj)
                acc[fi][fj] = __builtin_amdgcn_mfma_f32_16x16x32_bf16(
                    a[fi], b[fj], acc[fi][fj], 0, 0, 0);
        __syncthreads();                     // next buf resident; cur buf free
    }
#undef STAGE

    const float INF = __builtin_inff();

    // Operand-folded masking: invalid rows/cols contribute +INF.
    float xie[16], yje[4];
#pragma unroll
    for (int t = 0; t < 16; ++t) {
        int i = ibase + ((t >> 2) << 4) + (kg << 2) + (t & 3);
        xie[t] = (i < n1) ? sx2[i] : INF;
    }
#pragma unroll
    for (int fj = 0; fj < 4; ++fj) {
        int j = jbase + (fj << 4) + rf;
        yje[fj] = (j < n2) ? sy2[j] : INF;
    }

    float minj[4], mini[16];
#pragma unroll
    for (int fj = 0; fj < 4; ++fj) minj[fj] = INF;
#pragma unroll
    for (int t = 0; t < 16; ++t) mini[t] = INF;

#pragma unroll
    for (int fi = 0; fi < 4; ++fi) {
        float u[4][4];
#pragma unroll
        for (int fj = 0; fj < 4; ++fj)
#pragma unroll
            for (int q = 0; q < 4; ++q)
                u[fj][q] = fmaf(acc[fi][fj][q], -2.f, xie[fi * 4 + q] + yje[fj]);
#pragma unroll
        for (int fj = 0; fj < 4; ++fj) {
            minj[fj] = fminf(fminf(minj[fj], u[fj][0]), u[fj][1]);
            minj[fj] = fminf(fminf(minj[fj], u[fj][2]), u[fj][3]);
        }
#pragma unroll
        for (int q = 0; q < 4; ++q) {
            float mt = mini[fi * 4 + q];
            mt = fminf(fminf(mt, u[0][q]), u[1][q]);
            mt = fminf(fminf(mt, u[2][q]), u[3][q]);
            mini[fi * 4 + q] = mt;
        }
    }

    // Merge-reduce mini over rf lanes (acc bit k folded with lane bit k).
#pragma unroll
    for (int k = 0; k < 4; ++k) {
        const int d = 1 << k;
        const bool hi = (lane >> k) & 1;
#pragma unroll
        for (int base = 0; base < 16; base += 2 * (1 << k)) {
            float pa = fminf(mini[base], __shfl_xor(mini[base], d));
            float pb = fminf(mini[base + d], __shfl_xor(mini[base + d], d));
            mini[base] = hi ? pb : pa;
        }
    }
    {
        float dmin = __builtin_amdgcn_sqrtf(fmaxf(mini[0], 0.f));
        int i = ibase + ((rf >> 2) << 4) + (kg << 2) + (rf & 3);
        atomicMin(&sbm2[i], __float_as_uint(dmin));
    }

    // Merge-reduce minj over kg lanes (acc bit k with lane bit 4+k).
#pragma unroll
    for (int k = 0; k < 2; ++k) {
        const int d = 16 << k;
        const bool hi = (lane >> (4 + k)) & 1;
#pragma unroll
        for (int base = 0; base < 4; base += 2 * (1 << k)) {
            float pa = fminf(minj[base], __shfl_xor(minj[base], d));
            float pb = fminf(minj[base + (1 << k)],
                             __shfl_xor(minj[base + (1 << k)], d));
            minj[base] = hi ? pb : pa;
        }
    }
    {
        float dmin = __builtin_amdgcn_sqrtf(fmaxf(minj[0], 0.f));
        atomicMin(&sbm1[jbase + lane], __float_as_uint(dmin));
    }
    __syncthreads();

    float v = 0.f;
    if (tid < 128) {
        if (n1 > 0 && tid < n2) v += __uint_as_float(sbm1[tid]);
        if (n2 > 0 && tid < n1) v += __uint_as_float(sbm2[tid]);
    }
#pragma unroll
    for (int off = 32; off >= 1; off >>= 1) v += __shfl_down(v, off);
    if (lane == 0) swsum[wid] = v;
    __syncthreads();
    if (tid == 0) out[bid] = swsum[0] + swsum[1] + swsum[2] + swsum[3];
}

extern "C" void kernel_launch(void* const* d_in, const int* in_sizes, int n_in,
                              void* d_out, int out_size, void* d_ws, size_t ws_size,
                              hipStream_t stream) {
    const float* v1  = (const float*)d_in[0];
    const int*   sz1 = (const int*)d_in[1];
    const float* v2  = (const float*)d_in[2];
    const int*   sz2 = (const int*)d_in[3];
    float* out = (float*)d_out;
    (void)in_sizes; (void)n_in; (void)out_size; (void)ws_size;

    char* ws = (char*)d_ws;
    ushort_t* v1b = (ushort_t*)ws;                       // 2 MB
    ushort_t* v2b = (ushort_t*)(ws + (2u << 20));        // 2 MB
    float*    x2g = (float*)(ws + (4u << 20));           // 32 KB
    float*    y2g = x2g + 64 * 128;                      // 32 KB

    softhd_pre<<<dim3(1024), dim3(256), 0, stream>>>(v1, v2, v1b, v2b, x2g, y2g);
    softhd_mfma<<<dim3(4096), dim3(256), 0, stream>>>(v1b, v2b, x2g, y2g,
                                                      sz1, sz2, out);
}